// Round 3
// baseline (4963.721 us; speedup 1.0000x reference)
//
#include <hip/hip_runtime.h>

typedef unsigned short u16;
typedef __attribute__((ext_vector_type(8))) short short8;
typedef __attribute__((ext_vector_type(4))) float f32x4;
typedef __attribute__((ext_vector_type(2))) float f32x2;

#define S_ 512
#define I_ 512
#define H_ 1024
#define B_ 32
#define G_ 4096   // 4*H
#define WROW 1536 // I+H

__device__ __forceinline__ u16 f2b(float f){ union{float f;unsigned u;}c; c.f=f; unsigned u=c.u; return (u16)((u + 0x7FFFu + ((u>>16)&1u))>>16); }

// pack two fp32 (already bf16-rounded) into two bf16 lanes by truncation (exact)
__device__ __forceinline__ unsigned pk2(float a, float b){
  union{float f;unsigned u;} x, y; x.f=a; y.f=b;
  return (x.u>>16) | (y.u & 0xffff0000u);
}
// 8 consecutive fp32 -> short8 bf16 fragment
__device__ __forceinline__ short8 cvt8(const float* __restrict__ p){
  f32x4 a = *(const f32x4*)p;
  f32x4 b = *(const f32x4*)(p+4);
  union{unsigned u[4]; short8 s;} r;
  r.u[0]=pk2(a[0],a[1]); r.u[1]=pk2(a[2],a[3]);
  r.u[2]=pk2(b[0],b[1]); r.u[3]=pk2(b[2],b[3]);
  return r.s;
}

__device__ __forceinline__ f32x4 mfma16(short8 a, short8 b, f32x4 c){
  return __builtin_amdgcn_mfma_f32_16x16x32_bf16(a,b,c,0,0,0);
}
__device__ __forceinline__ float sigf(float x){ return 1.0f/(1.0f+__expf(-x)); }
__device__ __forceinline__ float tanhfast(float x){ return 1.0f - 2.0f/(__expf(2.0f*x)+1.0f); }

// ---------------------------------------------------------------------------
// Phase 1 (per chunk): xg[sl][g][b] = sum_i x[b][t0+sl][i]*W[g][i] + bias[g]
// fp32 in, fp32 out. grid: (64 gate-tiles of 64, CH/8 s-groups), block 256.
// ---------------------------------------------------------------------------
__global__ __launch_bounds__(256,2) void k_xg(
    const float* __restrict__ x,
    const float* __restrict__ Wf, const float* __restrict__ Wi,
    const float* __restrict__ Wo, const float* __restrict__ Wc,
    const float* __restrict__ bfp, const float* __restrict__ bip,
    const float* __restrict__ bop, const float* __restrict__ bcp,
    float* __restrict__ xg, int t0)
{
  const int gt = blockIdx.x;
  const int sg = blockIdx.y;
  const int wv = threadIdx.x>>6;
  const int ln = threadIdx.x&63;
  const int n16 = ln&15, qd = ln>>4;
  const int g0 = gt*64 + wv*16;
  const int q = g0>>10, j0 = g0&1023;
  const float* W  = (q==0)?Wf:(q==1)?Wi:(q==2)?Wo:Wc;
  const float* bb = (q==0)?bfp:(q==1)?bip:(q==2)?bop:bcp;

  short8 Bf[16];
  {
    const float* wr = W + (size_t)(j0+n16)*WROW + qd*8;
    #pragma unroll
    for(int kt=0;kt<16;++kt) Bf[kt] = cvt8(wr + kt*32);
  }
  const float bv = bb[j0+n16];

  for(int si=0; si<8; ++si){
    const int sl = sg*8 + si;
    const int s  = t0 + sl;
    const float* xp = x + (size_t)n16*(S_*I_) + (size_t)s*I_ + qd*8;
    f32x4 a0={0,0,0,0}, a1={0,0,0,0};
    #pragma unroll
    for(int kt=0;kt<16;++kt){
      short8 A0 = cvt8(xp + kt*32);
      short8 A1 = cvt8(xp + (size_t)16*(S_*I_) + kt*32);
      a0 = mfma16(A0, Bf[kt], a0);
      a1 = mfma16(A1, Bf[kt], a1);
    }
    float* op = xg + ((size_t)sl*G_ + g0 + n16)*B_ + qd*4;
    f32x4 o0, o1;
    #pragma unroll
    for(int r=0;r<4;++r){ o0[r]=a0[r]+bv; o1[r]=a1[r]+bv; }
    *(f32x4*)op = o0;
    *(f32x4*)(op+16) = o1;
  }
}

// ---------------------------------------------------------------------------
// Phase 2 (per chunk): persistent cooperative recurrence. 64 blocks x 256 thr.
// block bid owns h-indices [bid*16,+16) => 64 gate rows (4 gates x 16).
// Wh slice in VGPRs as bf16 frags (waves K-split 4x256). h double-buffered
// bf16 in global hbuf; c carried fp32 in cbuf across chunks; cnt monotonic.
// ---------------------------------------------------------------------------
__global__ __launch_bounds__(256,1) void k_rec(
  const float* __restrict__ xg,
  const float* __restrict__ Wf, const float* __restrict__ Wi,
  const float* __restrict__ Wo, const float* __restrict__ Wc,
  u16* __restrict__ hbuf,   // [2][32][1024] bf16
  u16* __restrict__ hs,     // [32][CH][1024] bf16 (chunk-local)
  float* __restrict__ hfin, float* __restrict__ cfin,
  float* __restrict__ cbuf, // [32][1024] f32
  unsigned* __restrict__ cnt,
  int t0, int CH)
{
  const int bid = blockIdx.x;
  const int h0  = bid*16;
  const int tid = threadIdx.x;
  const int kw  = tid>>6;          // wave index = K-slice
  const int ln  = tid&63;
  const int n16 = ln&15, qd = ln>>4;

  __shared__ float pbuf[4][4][16][36]; // [kw][q][hi][b(32)+4 pad] = 36 KB

  // Wh B-frags: Bf[q][k], k-slice = kw*256 .. +255  (fp32 -> bf16, exact)
  short8 Bf[4][8];
  {
    const int kcol = 512 + kw*256 + qd*8;
    const float* w0 = Wf + (size_t)(h0+n16)*WROW + kcol;
    const float* w1 = Wi + (size_t)(h0+n16)*WROW + kcol;
    const float* w2 = Wo + (size_t)(h0+n16)*WROW + kcol;
    const float* w3 = Wc + (size_t)(h0+n16)*WROW + kcol;
    #pragma unroll
    for(int k=0;k<8;++k){
      Bf[0][k] = cvt8(w0 + k*32);
      Bf[1][k] = cvt8(w1 + k*32);
      Bf[2][k] = cvt8(w2 + k*32);
      Bf[3][k] = cvt8(w3 + k*32);
    }
  }

  const int ub  = tid>>4;   // b of elem0 (0..15); elem1 = ub+16
  const int uhi = tid&15;
  float c0 = cbuf[(size_t)ub*H_      + h0 + uhi];
  float c1 = cbuf[(size_t)(ub+16)*H_ + h0 + uhi];

  for(int tl=0; tl<CH; ++tl){
    const int t = t0 + tl;
    // xg prefetch for the cell update (independent of h(t))
    float xv[2][4];
    {
      const float* xp = xg + ((size_t)tl*G_ + h0 + uhi)*B_;
      #pragma unroll
      for(int q=0;q<4;++q){
        xv[0][q] = xp[(size_t)q*1024*B_ + ub];
        xv[1][q] = xp[(size_t)q*1024*B_ + ub + 16];
      }
    }
    if (t>0){
      if (tid==0){
        const unsigned goal = (unsigned)t*64u;
        while (__hip_atomic_load(cnt, __ATOMIC_RELAXED, __HIP_MEMORY_SCOPE_AGENT) < goal)
          __builtin_amdgcn_s_sleep(2);
        __threadfence();   // acquire
      }
      __syncthreads();
    }
    // A-frags: h(t) rows (bf16), this wave's K-slice
    const u16* hp = hbuf + (size_t)(t&1)*(B_*H_) + kw*256 + qd*8;
    f32x4 acc[2][4];
    #pragma unroll
    for(int m=0;m<2;++m)
      #pragma unroll
      for(int q=0;q<4;++q) acc[m][q]=(f32x4){0.f,0.f,0.f,0.f};
    #pragma unroll
    for(int k=0;k<8;++k){
      short8 A0 = *(const short8*)(hp + (size_t)(n16)*H_    + k*32);
      short8 A1 = *(const short8*)(hp + (size_t)(16+n16)*H_ + k*32);
      #pragma unroll
      for(int q=0;q<4;++q){
        acc[0][q] = mfma16(A0, Bf[q][k], acc[0][q]);
        acc[1][q] = mfma16(A1, Bf[q][k], acc[1][q]);
      }
    }
    // partial-sum exchange: D col = gate sub-index (n16), rows = b
    #pragma unroll
    for(int m=0;m<2;++m)
      #pragma unroll
      for(int q=0;q<4;++q){
        float* dst = &pbuf[kw][q][n16][m*16 + qd*4];
        *(f32x2*)dst       = (f32x2){acc[m][q][0], acc[m][q][1]};
        *(f32x2*)(dst + 2) = (f32x2){acc[m][q][2], acc[m][q][3]};
      }
    __syncthreads();
    // cell update: thread handles (b=ub, hi=uhi) and (b=ub+16, hi=uhi)
    float g[2][4];
    #pragma unroll
    for(int e=0;e<2;++e){
      const int b = ub + e*16;
      #pragma unroll
      for(int q=0;q<4;++q){
        g[e][q] = xv[e][q] + pbuf[0][q][uhi][b] + pbuf[1][q][uhi][b]
                           + pbuf[2][q][uhi][b] + pbuf[3][q][uhi][b];
      }
    }
    u16* hw = hbuf + (size_t)((t+1)&1)*(B_*H_) + h0 + uhi;
    #pragma unroll
    for(int e=0;e<2;++e){
      const int b = ub + e*16;
      float fg = sigf(g[e][0]);
      float ig = sigf(g[e][1]);
      float og = sigf(g[e][2]);
      float ch = tanhfast(g[e][3]);
      float cp = e ? c1 : c0;
      float cn = fg*cp + ig*ch;
      if (e) c1 = cn; else c0 = cn;
      float hv = og*tanhfast(cn);
      u16 hb = f2b(hv);
      hw[(size_t)b*H_] = hb;
      hs[((size_t)b*CH + tl)*H_ + h0 + uhi] = hb;
      if (t==511){
        hfin[(size_t)b*H_ + h0 + uhi] = hv;
        cfin[(size_t)b*H_ + h0 + uhi] = cn;
      }
    }
    if (tl==CH-1){
      cbuf[(size_t)ub*H_      + h0 + uhi] = c0;
      cbuf[(size_t)(ub+16)*H_ + h0 + uhi] = c1;
    }
    __syncthreads();              // drains this block's stores
    if (tid==0){
      __threadfence();            // release
      __hip_atomic_fetch_add(cnt, 1u, __ATOMIC_RELAXED, __HIP_MEMORY_SCOPE_AGENT);
    }
  }
}

// ---------------------------------------------------------------------------
// Phase 3 (per chunk): out[b][t0+sl][o] = sum_h hs[b][sl][h]*ow[o][h] + ob[o]
// hs bf16, ow/ob/out fp32. grid: (CH/2 row-tiles of 64, 8 o-tiles), block 256.
// ---------------------------------------------------------------------------
__global__ __launch_bounds__(256,2) void k_out(
  const u16* __restrict__ hs,
  const float* __restrict__ ow,
  const float* __restrict__ obp,
  float* __restrict__ out, int t0, int chlog)
{
  const int bst = blockIdx.x;
  const int ot  = blockIdx.y;
  const int wv = threadIdx.x>>6;
  const int ln = threadIdx.x&63;
  const int n16 = ln&15, qd = ln>>4;
  const int bs0 = bst*64 + wv*16 + n16;   // row in hs_chunk = b*CH + sl
  const u16* bp   = hs + (size_t)bs0*H_ + qd*8;
  const float* ap = ow + (size_t)(ot*64 + n16)*H_ + qd*8;
  f32x4 acc[4];
  #pragma unroll
  for(int m=0;m<4;++m) acc[m]=(f32x4){0.f,0.f,0.f,0.f};
  #pragma unroll 4
  for(int kt=0;kt<32;++kt){
    short8 Bfr = *(const short8*)(bp + kt*32);
    #pragma unroll
    for(int m=0;m<4;++m){
      short8 Afr = cvt8(ap + (size_t)m*16*H_ + kt*32);
      acc[m] = mfma16(Afr, Bfr, acc[m]);
    }
  }
  const int b  = bs0 >> chlog;
  const int sl = bs0 & ((1<<chlog)-1);
  float* orow = out + ((size_t)b*S_ + t0 + sl)*512;
  #pragma unroll
  for(int m=0;m<4;++m){
    const int o0 = ot*64 + m*16 + qd*4;
    f32x4 ov;
    #pragma unroll
    for(int r=0;r<4;++r) ov[r] = acc[m][r] + obp[o0+r];
    *(f32x4*)(orow + o0) = ov;
  }
}

// ---------------------------------------------------------------------------
extern "C" void kernel_launch(void* const* d_in, const int* in_sizes, int n_in,
                              void* d_out, int out_size, void* d_ws, size_t ws_size,
                              hipStream_t stream)
{
  const float* x  = (const float*)d_in[0];
  const float* Wf = (const float*)d_in[1];
  const float* bf = (const float*)d_in[2];
  const float* Wi = (const float*)d_in[3];
  const float* bi = (const float*)d_in[4];
  const float* Wo = (const float*)d_in[5];
  const float* bo = (const float*)d_in[6];
  const float* Wc = (const float*)d_in[7];
  const float* bc = (const float*)d_in[8];
  const float* ow = (const float*)d_in[9];
  const float* ob = (const float*)d_in[10];
  float* out = (float*)d_out;

  // workspace: fixed 262656 B (cnt 512 + hbuf 128K bf16 + cbuf 128K f32)
  //          + CH*589824 B (xg fp32 CH*512K + hs bf16 CH*64K)
  const size_t fixed = 262656;
  int CH = 256, chlog = 8;
  while (CH > 16 && fixed + (size_t)CH*589824 > ws_size){ CH >>= 1; chlog--; }
  const int NC = 512 / CH;

  char* ws = (char*)d_ws;
  unsigned* cnt = (unsigned*)ws;                       // 512 B
  u16*   hbuf = (u16*)(ws + 512);                      // 128 KB
  float* cbuf = (float*)(ws + 131584);                 // 128 KB
  float* xg   = (float*)(ws + 262656);                 // CH*512 KB
  u16*   hsc  = (u16*)(ws + 262656 + (size_t)CH*524288); // CH*64 KB
  float* hfin = out + (size_t)8388608;
  float* cfin = out + (size_t)8421376;

  hipMemsetAsync(ws, 0, fixed, stream);  // cnt=0, h(0)=0, c(0)=0

  for(int c=0; c<NC; ++c){
    int t0 = c*CH;
    k_xg<<<dim3(64,CH/8),256,0,stream>>>(x,Wf,Wi,Wo,Wc,bf,bi,bo,bc,xg,t0);

    const float* a_xg = xg;
    int a_t0 = t0, a_ch = CH;
    void* args[] = { (void*)&a_xg, (void*)&Wf, (void*)&Wi, (void*)&Wo, (void*)&Wc,
                     (void*)&hbuf, (void*)&hsc, (void*)&hfin, (void*)&cfin,
                     (void*)&cbuf, (void*)&cnt, (void*)&a_t0, (void*)&a_ch };
    hipLaunchCooperativeKernel((const void*)k_rec, dim3(64), dim3(256), args, 0, stream);

    k_out<<<dim3(CH/2,8),256,0,stream>>>(hsc, ow, ob, out, t0, chlog);
  }
}

// Round 5
// 4847.474 us; speedup vs baseline: 1.0240x; 1.0240x over previous
//
#include <hip/hip_runtime.h>

typedef unsigned short u16;
typedef __attribute__((ext_vector_type(8))) short short8;
typedef __attribute__((ext_vector_type(4))) float f32x4;
typedef __attribute__((ext_vector_type(2))) float f32x2;

#define S_ 512
#define I_ 512
#define H_ 1024
#define B_ 32
#define G_ 4096   // 4*H
#define WROW 1536 // I+H

__device__ __forceinline__ u16 f2b(float f){ union{float f;unsigned u;}c; c.f=f; unsigned u=c.u; return (u16)((u + 0x7FFFu + ((u>>16)&1u))>>16); }

// pack two fp32 (already bf16-rounded) into two bf16 lanes by truncation (exact)
// NOTE: v_perm_b32 variant broke correctness in R4 (operand-order ambiguity);
// shifts are proven. Do not re-introduce perm without an isolated A/B test.
__device__ __forceinline__ unsigned pk2(float a, float b){
  union{float f;unsigned u;} x, y; x.f=a; y.f=b;
  return (x.u>>16) | (y.u & 0xffff0000u);
}
// 8 consecutive fp32 -> short8 bf16 fragment
__device__ __forceinline__ short8 cvt8(const float* __restrict__ p){
  f32x4 a = *(const f32x4*)p;
  f32x4 b = *(const f32x4*)(p+4);
  union{unsigned u[4]; short8 s;} r;
  r.u[0]=pk2(a[0],a[1]); r.u[1]=pk2(a[2],a[3]);
  r.u[2]=pk2(b[0],b[1]); r.u[3]=pk2(b[2],b[3]);
  return r.s;
}

__device__ __forceinline__ f32x4 mfma16(short8 a, short8 b, f32x4 c){
  return __builtin_amdgcn_mfma_f32_16x16x32_bf16(a,b,c,0,0,0);
}
__device__ __forceinline__ float sigf(float x){ return 1.0f/(1.0f+__expf(-x)); }
__device__ __forceinline__ float tanhfast(float x){ return 1.0f - 2.0f/(__expf(2.0f*x)+1.0f); }

// ---------------------------------------------------------------------------
// Phase 1 (per chunk): xg[sl][g][b] = sum_i x[b][t0+sl][i]*W[g][i] + bias[g]
// fp32 in, fp32 out. grid: (64 gate-tiles of 64, CH/8 s-groups), block 256.
// ---------------------------------------------------------------------------
__global__ __launch_bounds__(256,2) void k_xg(
    const float* __restrict__ x,
    const float* __restrict__ Wf, const float* __restrict__ Wi,
    const float* __restrict__ Wo, const float* __restrict__ Wc,
    const float* __restrict__ bfp, const float* __restrict__ bip,
    const float* __restrict__ bop, const float* __restrict__ bcp,
    float* __restrict__ xg, int t0)
{
  const int gt = blockIdx.x;
  const int sg = blockIdx.y;
  const int wv = threadIdx.x>>6;
  const int ln = threadIdx.x&63;
  const int n16 = ln&15, qd = ln>>4;
  const int g0 = gt*64 + wv*16;
  const int q = g0>>10, j0 = g0&1023;
  const float* W  = (q==0)?Wf:(q==1)?Wi:(q==2)?Wo:Wc;
  const float* bb = (q==0)?bfp:(q==1)?bip:(q==2)?bop:bcp;

  short8 Bf[16];
  {
    const float* wr = W + (size_t)(j0+n16)*WROW + qd*8;
    #pragma unroll
    for(int kt=0;kt<16;++kt) Bf[kt] = cvt8(wr + kt*32);
  }
  const float bv = bb[j0+n16];

  for(int si=0; si<8; ++si){
    const int sl = sg*8 + si;
    const int s  = t0 + sl;
    const float* xp = x + (size_t)n16*(S_*I_) + (size_t)s*I_ + qd*8;
    f32x4 a0={0,0,0,0}, a1={0,0,0,0};
    #pragma unroll
    for(int kt=0;kt<16;++kt){
      short8 A0 = cvt8(xp + kt*32);
      short8 A1 = cvt8(xp + (size_t)16*(S_*I_) + kt*32);
      a0 = mfma16(A0, Bf[kt], a0);
      a1 = mfma16(A1, Bf[kt], a1);
    }
    float* op = xg + ((size_t)sl*G_ + g0 + n16)*B_ + qd*4;
    f32x4 o0, o1;
    #pragma unroll
    for(int r=0;r<4;++r){ o0[r]=a0[r]+bv; o1[r]=a1[r]+bv; }
    *(f32x4*)op = o0;
    *(f32x4*)(op+16) = o1;
  }
}

// ---------------------------------------------------------------------------
// Phase 2 (per chunk): persistent cooperative recurrence. 64 blocks x 256 thr.
// block bid owns h-indices [bid*16,+16) => 64 gate rows (4 gates x 16).
// Wh slice in VGPRs as bf16 frags (waves K-split 4x256). h double-buffered
// bf16 in global hbuf; c carried fp32 in cbuf across chunks.
// Barrier: 64 distributed flags (one 128B line per block), monotone step
// counter; wave0 lanes poll one flag each (no serialized central atomic).
// ---------------------------------------------------------------------------
__global__ __launch_bounds__(256,1) void k_rec(
  const float* __restrict__ xg,
  const float* __restrict__ Wf, const float* __restrict__ Wi,
  const float* __restrict__ Wo, const float* __restrict__ Wc,
  u16* __restrict__ hbuf,   // [2][32][1024] bf16
  u16* __restrict__ hs,     // [32][CH][1024] bf16 (chunk-local)
  float* __restrict__ hfin, float* __restrict__ cfin,
  float* __restrict__ cbuf, // [32][1024] f32
  unsigned* __restrict__ flags, // 64 x 32 u32 (128B apart)
  int t0, int CH)
{
  const int bid = blockIdx.x;
  const int h0  = bid*16;
  const int tid = threadIdx.x;
  const int kw  = tid>>6;          // wave index = K-slice
  const int ln  = tid&63;
  const int n16 = ln&15, qd = ln>>4;

  __shared__ float pbuf[4][4][16][38]; // pad 38: write banks 6*n16+4*qd ~2-way

  // Wh B-frags: Bf[q][k], k-slice = kw*256 .. +255  (fp32 -> bf16, exact)
  short8 Bf[4][8];
  {
    const int kcol = 512 + kw*256 + qd*8;
    const float* w0 = Wf + (size_t)(h0+n16)*WROW + kcol;
    const float* w1 = Wi + (size_t)(h0+n16)*WROW + kcol;
    const float* w2 = Wo + (size_t)(h0+n16)*WROW + kcol;
    const float* w3 = Wc + (size_t)(h0+n16)*WROW + kcol;
    #pragma unroll
    for(int k=0;k<8;++k){
      Bf[0][k] = cvt8(w0 + k*32);
      Bf[1][k] = cvt8(w1 + k*32);
      Bf[2][k] = cvt8(w2 + k*32);
      Bf[3][k] = cvt8(w3 + k*32);
    }
  }

  const int ub  = tid>>4;   // b of elem0 (0..15); elem1 = ub+16
  const int uhi = tid&15;
  float c0 = cbuf[(size_t)ub*H_      + h0 + uhi];
  float c1 = cbuf[(size_t)(ub+16)*H_ + h0 + uhi];

  for(int tl=0; tl<CH; ++tl){
    const int t = t0 + tl;
    // xg prefetch for the cell update (independent of h(t))
    float xv[2][4];
    {
      const float* xp = xg + ((size_t)tl*G_ + h0 + uhi)*B_;
      #pragma unroll
      for(int q=0;q<4;++q){
        xv[0][q] = xp[(size_t)q*1024*B_ + ub];
        xv[1][q] = xp[(size_t)q*1024*B_ + ub + 16];
      }
    }
    if (t>0){
      if (tid < 64){
        const unsigned goal = (unsigned)t;
        unsigned v;
        do {
          v = __hip_atomic_load(flags + (tid<<5), __ATOMIC_RELAXED, __HIP_MEMORY_SCOPE_AGENT);
          if (__ballot(v < goal) == 0ull) break;
          __builtin_amdgcn_s_sleep(1);
        } while (true);
        if (tid==0) __threadfence();   // acquire: invalidate stale L1/L2
      }
      __syncthreads();
    }
    // A-frags: h(t) rows (bf16), this wave's K-slice
    const u16* hp = hbuf + (size_t)(t&1)*(B_*H_) + kw*256 + qd*8;
    f32x4 acc[2][4];
    #pragma unroll
    for(int m=0;m<2;++m)
      #pragma unroll
      for(int q=0;q<4;++q) acc[m][q]=(f32x4){0.f,0.f,0.f,0.f};
    #pragma unroll
    for(int k=0;k<8;++k){
      short8 A0 = *(const short8*)(hp + (size_t)(n16)*H_    + k*32);
      short8 A1 = *(const short8*)(hp + (size_t)(16+n16)*H_ + k*32);
      #pragma unroll
      for(int q=0;q<4;++q){
        acc[0][q] = mfma16(A0, Bf[q][k], acc[0][q]);
        acc[1][q] = mfma16(A1, Bf[q][k], acc[1][q]);
      }
    }
    // partial-sum exchange: D col = gate sub-index (n16), rows = b
    #pragma unroll
    for(int m=0;m<2;++m)
      #pragma unroll
      for(int q=0;q<4;++q){
        float* dst = &pbuf[kw][q][n16][m*16 + qd*4];
        *(f32x2*)dst       = (f32x2){acc[m][q][0], acc[m][q][1]};
        *(f32x2*)(dst + 2) = (f32x2){acc[m][q][2], acc[m][q][3]};
      }
    __syncthreads();
    // cell update: thread handles (b=ub, hi=uhi) and (b=ub+16, hi=uhi)
    float g[2][4];
    #pragma unroll
    for(int e=0;e<2;++e){
      const int b = ub + e*16;
      #pragma unroll
      for(int q=0;q<4;++q){
        g[e][q] = xv[e][q] + pbuf[0][q][uhi][b] + pbuf[1][q][uhi][b]
                           + pbuf[2][q][uhi][b] + pbuf[3][q][uhi][b];
      }
    }
    u16* hw = hbuf + (size_t)((t+1)&1)*(B_*H_) + h0 + uhi;
    #pragma unroll
    for(int e=0;e<2;++e){
      const int b = ub + e*16;
      float fg = sigf(g[e][0]);
      float ig = sigf(g[e][1]);
      float og = sigf(g[e][2]);
      float ch = tanhfast(g[e][3]);
      float cp = e ? c1 : c0;
      float cn = fg*cp + ig*ch;
      if (e) c1 = cn; else c0 = cn;
      float hv = og*tanhfast(cn);
      u16 hb = f2b(hv);
      hw[(size_t)b*H_] = hb;
      hs[((size_t)b*CH + tl)*H_ + h0 + uhi] = hb;
      if (t==511){
        hfin[(size_t)b*H_ + h0 + uhi] = hv;
        cfin[(size_t)b*H_ + h0 + uhi] = cn;
      }
    }
    if (tl==CH-1){
      cbuf[(size_t)ub*H_      + h0 + uhi] = c0;
      cbuf[(size_t)(ub+16)*H_ + h0 + uhi] = c1;
    }
    __syncthreads();              // drains this block's stores
    if (tid==0){
      __threadfence();            // release: L2 writeback
      __hip_atomic_store(flags + (bid<<5), (unsigned)(t+1),
                         __ATOMIC_RELAXED, __HIP_MEMORY_SCOPE_AGENT);
    }
  }
}

// ---------------------------------------------------------------------------
// Phase 3 (per chunk): out[b][t0+sl][o] = sum_h hs[b][sl][h]*ow[o][h] + ob[o]
// hs bf16, ow/ob/out fp32. grid: (CH/2 row-tiles of 64, 8 o-tiles), block 256.
// ---------------------------------------------------------------------------
__global__ __launch_bounds__(256,2) void k_out(
  const u16* __restrict__ hs,
  const float* __restrict__ ow,
  const float* __restrict__ obp,
  float* __restrict__ out, int t0, int chlog)
{
  const int bst = blockIdx.x;
  const int ot  = blockIdx.y;
  const int wv = threadIdx.x>>6;
  const int ln = threadIdx.x&63;
  const int n16 = ln&15, qd = ln>>4;
  const int bs0 = bst*64 + wv*16 + n16;   // row in hs_chunk = b*CH + sl
  const u16* bp   = hs + (size_t)bs0*H_ + qd*8;
  const float* ap = ow + (size_t)(ot*64 + n16)*H_ + qd*8;
  f32x4 acc[4];
  #pragma unroll
  for(int m=0;m<4;++m) acc[m]=(f32x4){0.f,0.f,0.f,0.f};
  #pragma unroll 4
  for(int kt=0;kt<32;++kt){
    short8 Bfr = *(const short8*)(bp + kt*32);
    #pragma unroll
    for(int m=0;m<4;++m){
      short8 Afr = cvt8(ap + (size_t)m*16*H_ + kt*32);
      acc[m] = mfma16(Afr, Bfr, acc[m]);
    }
  }
  const int b  = bs0 >> chlog;
  const int sl = bs0 & ((1<<chlog)-1);
  float* orow = out + ((size_t)b*S_ + t0 + sl)*512;
  #pragma unroll
  for(int m=0;m<4;++m){
    const int o0 = ot*64 + m*16 + qd*4;
    f32x4 ov;
    #pragma unroll
    for(int r=0;r<4;++r) ov[r] = acc[m][r] + obp[o0+r];
    *(f32x4*)(orow + o0) = ov;
  }
}

// ---------------------------------------------------------------------------
extern "C" void kernel_launch(void* const* d_in, const int* in_sizes, int n_in,
                              void* d_out, int out_size, void* d_ws, size_t ws_size,
                              hipStream_t stream)
{
  const float* x  = (const float*)d_in[0];
  const float* Wf = (const float*)d_in[1];
  const float* bf = (const float*)d_in[2];
  const float* Wi = (const float*)d_in[3];
  const float* bi = (const float*)d_in[4];
  const float* Wo = (const float*)d_in[5];
  const float* bo = (const float*)d_in[6];
  const float* Wc = (const float*)d_in[7];
  const float* bc = (const float*)d_in[8];
  const float* ow = (const float*)d_in[9];
  const float* ob = (const float*)d_in[10];
  float* out = (float*)d_out;

  // workspace: fixed 270336 B (flags 8K + hbuf 128K bf16 + cbuf 128K f32)
  //          + CH*589824 B (xg fp32 CH*512K + hs bf16 CH*64K)
  const size_t fixed = 270336;
  int CH = 256, chlog = 8;
  while (CH > 16 && fixed + (size_t)CH*589824 > ws_size){ CH >>= 1; chlog--; }
  const int NC = 512 / CH;

  char* ws = (char*)d_ws;
  unsigned* flags = (unsigned*)ws;                     // 8 KB (64 x 128B)
  u16*   hbuf = (u16*)(ws + 8192);                     // 128 KB
  float* cbuf = (float*)(ws + 139264);                 // 128 KB
  float* xg   = (float*)(ws + 270336);                 // CH*512 KB
  u16*   hsc  = (u16*)(ws + 270336 + (size_t)CH*524288); // CH*64 KB
  float* hfin = out + (size_t)8388608;
  float* cfin = out + (size_t)8421376;

  hipMemsetAsync(ws, 0, fixed, stream);  // flags=0, h(0)=0, c(0)=0

  for(int c=0; c<NC; ++c){
    int t0 = c*CH;
    k_xg<<<dim3(64,CH/8),256,0,stream>>>(x,Wf,Wi,Wo,Wc,bf,bi,bo,bc,xg,t0);

    const float* a_xg = xg;
    int a_t0 = t0, a_ch = CH;
    void* args[] = { (void*)&a_xg, (void*)&Wf, (void*)&Wi, (void*)&Wo, (void*)&Wc,
                     (void*)&hbuf, (void*)&hsc, (void*)&hfin, (void*)&cfin,
                     (void*)&cbuf, (void*)&flags, (void*)&a_t0, (void*)&a_ch };
    hipLaunchCooperativeKernel((const void*)k_rec, dim3(64), dim3(256), args, 0, stream);

    k_out<<<dim3(CH/2,8),256,0,stream>>>(hsc, ow, ob, out, t0, chlog);
  }
}

// Round 7
// 4259.776 us; speedup vs baseline: 1.1653x; 1.1380x over previous
//
#include <hip/hip_runtime.h>

typedef unsigned short u16;
typedef unsigned long long u64;
typedef __attribute__((ext_vector_type(8))) short short8;
typedef __attribute__((ext_vector_type(4))) float f32x4;
typedef __attribute__((ext_vector_type(2))) float f32x2;

#define S_ 512
#define I_ 512
#define H_ 1024
#define B_ 32
#define G_ 4096   // 4*H
#define WROW 1536 // I+H

__device__ __forceinline__ u16 f2b(float f){ union{float f;unsigned u;}c; c.f=f; unsigned u=c.u; return (u16)((u + 0x7FFFu + ((u>>16)&1u))>>16); }

// pack two fp32 (already bf16-rounded) into two bf16 lanes by truncation (exact)
// NOTE: v_perm_b32 variant broke correctness in R4; shifts are proven.
__device__ __forceinline__ unsigned pk2(float a, float b){
  union{float f;unsigned u;} x, y; x.f=a; y.f=b;
  return (x.u>>16) | (y.u & 0xffff0000u);
}
// 8 consecutive fp32 -> short8 bf16 fragment
__device__ __forceinline__ short8 cvt8(const float* __restrict__ p){
  f32x4 a = *(const f32x4*)p;
  f32x4 b = *(const f32x4*)(p+4);
  union{unsigned u[4]; short8 s;} r;
  r.u[0]=pk2(a[0],a[1]); r.u[1]=pk2(a[2],a[3]);
  r.u[2]=pk2(b[0],b[1]); r.u[3]=pk2(b[2],b[3]);
  return r.s;
}

// coherent 16B fragment load via two agent-scope relaxed u64 atomic loads.
// Compiler-managed (correct sc bits + waitcnt tracking). NO inline asm:
// R6's asm global_load had an unfixable result-hazard (no VGPR scoreboard).
__device__ __forceinline__ short8 aload16(const u16* p){
  u64 lo = __hip_atomic_load((const u64*)p,     __ATOMIC_RELAXED, __HIP_MEMORY_SCOPE_AGENT);
  u64 hi = __hip_atomic_load((const u64*)(p+4), __ATOMIC_RELAXED, __HIP_MEMORY_SCOPE_AGENT);
  union{u64 q[2]; short8 s;} u; u.q[0]=lo; u.q[1]=hi; return u.s;
}

__device__ __forceinline__ f32x4 mfma16(short8 a, short8 b, f32x4 c){
  return __builtin_amdgcn_mfma_f32_16x16x32_bf16(a,b,c,0,0,0);
}
__device__ __forceinline__ float sigf(float x){ return 1.0f/(1.0f+__expf(-x)); }
__device__ __forceinline__ float tanhfast(float x){ return 1.0f - 2.0f/(__expf(2.0f*x)+1.0f); }

// ---------------------------------------------------------------------------
// Phase 1 (per chunk): xg[sl][g][b] = sum_i x[b][t0+sl][i]*W[g][i] + bias[g]
// (unchanged from R5)
// ---------------------------------------------------------------------------
__global__ __launch_bounds__(256,2) void k_xg(
    const float* __restrict__ x,
    const float* __restrict__ Wf, const float* __restrict__ Wi,
    const float* __restrict__ Wo, const float* __restrict__ Wc,
    const float* __restrict__ bfp, const float* __restrict__ bip,
    const float* __restrict__ bop, const float* __restrict__ bcp,
    float* __restrict__ xg, int t0)
{
  const int gt = blockIdx.x;
  const int sg = blockIdx.y;
  const int wv = threadIdx.x>>6;
  const int ln = threadIdx.x&63;
  const int n16 = ln&15, qd = ln>>4;
  const int g0 = gt*64 + wv*16;
  const int q = g0>>10, j0 = g0&1023;
  const float* W  = (q==0)?Wf:(q==1)?Wi:(q==2)?Wo:Wc;
  const float* bb = (q==0)?bfp:(q==1)?bip:(q==2)?bop:bcp;

  short8 Bf[16];
  {
    const float* wr = W + (size_t)(j0+n16)*WROW + qd*8;
    #pragma unroll
    for(int kt=0;kt<16;++kt) Bf[kt] = cvt8(wr + kt*32);
  }
  const float bv = bb[j0+n16];

  for(int si=0; si<8; ++si){
    const int sl = sg*8 + si;
    const int s  = t0 + sl;
    const float* xp = x + (size_t)n16*(S_*I_) + (size_t)s*I_ + qd*8;
    f32x4 a0={0,0,0,0}, a1={0,0,0,0};
    #pragma unroll
    for(int kt=0;kt<16;++kt){
      short8 A0 = cvt8(xp + kt*32);
      short8 A1 = cvt8(xp + (size_t)16*(S_*I_) + kt*32);
      a0 = mfma16(A0, Bf[kt], a0);
      a1 = mfma16(A1, Bf[kt], a1);
    }
    float* op = xg + ((size_t)sl*G_ + g0 + n16)*B_ + qd*4;
    f32x4 o0, o1;
    #pragma unroll
    for(int r=0;r<4;++r){ o0[r]=a0[r]+bv; o1[r]=a1[r]+bv; }
    *(f32x4*)op = o0;
    *(f32x4*)(op+16) = o1;
  }
}

// ---------------------------------------------------------------------------
// Phase 2: persistent cooperative recurrence, fence-free protocol with
// compiler-managed coherent atomics.
//  - h(t+1): relaxed agent-scope atomic u32 stores (ack'd at LLC)
//  - h(t):   relaxed agent-scope atomic u64 loads (read LLC)
//  - release: __syncthreads (compiler emits vmcnt(0) -> stores globally
//    visible) then relaxed flag store; consumer polls flags, no fences.
// Cell mapping: thread owns (b=tid>>3, hi=2*(tid&7)+{0,1}).
// ---------------------------------------------------------------------------
__global__ __launch_bounds__(256,1) void k_rec(
  const float* __restrict__ xg,
  const float* __restrict__ Wf, const float* __restrict__ Wi,
  const float* __restrict__ Wo, const float* __restrict__ Wc,
  u16* __restrict__ hbuf,   // [2][32][1024] bf16 (LLC-coherent traffic)
  u16* __restrict__ hs,     // [32][CH][1024] bf16 (chunk-local, plain)
  float* __restrict__ hfin, float* __restrict__ cfin,
  float* __restrict__ cbuf, // [32][1024] f32
  unsigned* __restrict__ flags, // 64 x 32 u32 (128B apart)
  int t0, int CH)
{
  const int bid = blockIdx.x;
  const int h0  = bid*16;
  const int tid = threadIdx.x;
  const int kw  = tid>>6;          // wave index = K-slice
  const int ln  = tid&63;
  const int n16 = ln&15, qd = ln>>4;

  __shared__ float pbuf[4][4][16][38]; // [kw][q][hi][b+pad]

  // Wh B-frags: Bf[q][k], k-slice = kw*256 .. +255  (fp32 -> bf16, exact)
  short8 Bf[4][8];
  {
    const int kcol = 512 + kw*256 + qd*8;
    const float* w0 = Wf + (size_t)(h0+n16)*WROW + kcol;
    const float* w1 = Wi + (size_t)(h0+n16)*WROW + kcol;
    const float* w2 = Wo + (size_t)(h0+n16)*WROW + kcol;
    const float* w3 = Wc + (size_t)(h0+n16)*WROW + kcol;
    #pragma unroll
    for(int k=0;k<8;++k){
      Bf[0][k] = cvt8(w0 + k*32);
      Bf[1][k] = cvt8(w1 + k*32);
      Bf[2][k] = cvt8(w2 + k*32);
      Bf[3][k] = cvt8(w3 + k*32);
    }
  }

  const int ub  = tid>>3;        // b (0..31)
  const int hi0 = (tid&7)*2;     // hi pair {hi0, hi0+1}
  f32x2 c01 = *(const f32x2*)(cbuf + (size_t)ub*H_ + h0 + hi0);

  for(int tl=0; tl<CH; ++tl){
    const int t = t0 + tl;
    // xg prefetch for the cell update (independent of h(t))
    float xv[2][4];
    {
      const float* xp = xg + ((size_t)tl*G_ + h0 + hi0)*B_ + ub;
      #pragma unroll
      for(int q=0;q<4;++q){
        xv[0][q] = xp[(size_t)q*1024*B_];
        xv[1][q] = xp[(size_t)q*1024*B_ + B_];
      }
    }
    if (t>0){
      if (tid < 64){
        const unsigned goal = (unsigned)t;
        unsigned v;
        do {
          v = __hip_atomic_load(flags + (tid<<5), __ATOMIC_RELAXED, __HIP_MEMORY_SCOPE_AGENT);
          if (__ballot(v < goal) == 0ull) break;
          __builtin_amdgcn_s_sleep(1);
        } while (true);
        // no fence: h loads below are agent-scope atomics (LLC-coherent)
      }
      __syncthreads();
    }
    // A-frags: h(t) rows (bf16), this wave's K-slice — coherent atomic loads
    const u16* hp = hbuf + (size_t)(t&1)*(B_*H_) + kw*256 + qd*8;
    const u16* hp0 = hp + (size_t)n16*H_;
    const u16* hp1 = hp + (size_t)(16+n16)*H_;
    f32x4 acc[2][4];
    #pragma unroll
    for(int m=0;m<2;++m)
      #pragma unroll
      for(int q=0;q<4;++q) acc[m][q]=(f32x4){0.f,0.f,0.f,0.f};
    #pragma unroll
    for(int k=0;k<8;++k){
      short8 A0 = aload16(hp0 + k*32);
      short8 A1 = aload16(hp1 + k*32);
      #pragma unroll
      for(int q=0;q<4;++q){
        acc[0][q] = mfma16(A0, Bf[q][k], acc[0][q]);
        acc[1][q] = mfma16(A1, Bf[q][k], acc[1][q]);
      }
    }
    // partial-sum exchange: D col = gate sub-index (n16), rows = b
    #pragma unroll
    for(int m=0;m<2;++m)
      #pragma unroll
      for(int q=0;q<4;++q){
        float* dst = &pbuf[kw][q][n16][m*16 + qd*4];
        *(f32x2*)dst       = (f32x2){acc[m][q][0], acc[m][q][1]};
        *(f32x2*)(dst + 2) = (f32x2){acc[m][q][2], acc[m][q][3]};
      }
    __syncthreads();
    // cell update: thread handles (b=ub, hi=hi0) and (b=ub, hi=hi0+1)
    float g[2][4];
    #pragma unroll
    for(int e=0;e<2;++e){
      #pragma unroll
      for(int q=0;q<4;++q){
        g[e][q] = xv[e][q] + pbuf[0][q][hi0+e][ub] + pbuf[1][q][hi0+e][ub]
                           + pbuf[2][q][hi0+e][ub] + pbuf[3][q][hi0+e][ub];
      }
    }
    float hv[2], cn[2];
    #pragma unroll
    for(int e=0;e<2;++e){
      float fg = sigf(g[e][0]);
      float ig = sigf(g[e][1]);
      float og = sigf(g[e][2]);
      float ch = tanhfast(g[e][3]);
      cn[e] = fg*c01[e] + ig*ch;
      hv[e] = og*tanhfast(cn[e]);
      c01[e] = cn[e];
    }
    const unsigned hpk = (unsigned)f2b(hv[0]) | ((unsigned)f2b(hv[1])<<16);
    // h(t+1): write-through to LLC (agent-scope relaxed atomic)
    unsigned* hw = (unsigned*)(hbuf + (size_t)((t+1)&1)*(B_*H_) + (size_t)ub*H_ + h0 + hi0);
    __hip_atomic_store(hw, hpk, __ATOMIC_RELAXED, __HIP_MEMORY_SCOPE_AGENT);
    // history (plain store, read by k_out after kernel end)
    *(unsigned*)(hs + ((size_t)ub*CH + tl)*H_ + h0 + hi0) = hpk;
    if (t==511){
      *(f32x2*)(hfin + (size_t)ub*H_ + h0 + hi0) = (f32x2){hv[0], hv[1]};
      *(f32x2*)(cfin + (size_t)ub*H_ + h0 + hi0) = (f32x2){cn[0], cn[1]};
    }
    if (tl==CH-1)
      *(f32x2*)(cbuf + (size_t)ub*H_ + h0 + hi0) = c01;
    __syncthreads();              // compiler emits vmcnt(0): h stores ack'd
    if (tid==0)
      __hip_atomic_store(flags + (bid<<5), (unsigned)(t+1),
                         __ATOMIC_RELAXED, __HIP_MEMORY_SCOPE_AGENT);
  }
}

// ---------------------------------------------------------------------------
// Phase 3 (per chunk): out[b][t0+sl][o] = sum_h hs[b][sl][h]*ow[o][h] + ob[o]
// (unchanged from R5)
// ---------------------------------------------------------------------------
__global__ __launch_bounds__(256,2) void k_out(
  const u16* __restrict__ hs,
  const float* __restrict__ ow,
  const float* __restrict__ obp,
  float* __restrict__ out, int t0, int chlog)
{
  const int bst = blockIdx.x;
  const int ot  = blockIdx.y;
  const int wv = threadIdx.x>>6;
  const int ln = threadIdx.x&63;
  const int n16 = ln&15, qd = ln>>4;
  const int bs0 = bst*64 + wv*16 + n16;   // row in hs_chunk = b*CH + sl
  const u16* bp   = hs + (size_t)bs0*H_ + qd*8;
  const float* ap = ow + (size_t)(ot*64 + n16)*H_ + qd*8;
  f32x4 acc[4];
  #pragma unroll
  for(int m=0;m<4;++m) acc[m]=(f32x4){0.f,0.f,0.f,0.f};
  #pragma unroll 4
  for(int kt=0;kt<32;++kt){
    short8 Bfr = *(const short8*)(bp + kt*32);
    #pragma unroll
    for(int m=0;m<4;++m){
      short8 Afr = cvt8(ap + (size_t)m*16*H_ + kt*32);
      acc[m] = mfma16(Afr, Bfr, acc[m]);
    }
  }
  const int b  = bs0 >> chlog;
  const int sl = bs0 & ((1<<chlog)-1);
  float* orow = out + ((size_t)b*S_ + t0 + sl)*512;
  #pragma unroll
  for(int m=0;m<4;++m){
    const int o0 = ot*64 + m*16 + qd*4;
    f32x4 ov;
    #pragma unroll
    for(int r=0;r<4;++r) ov[r] = acc[m][r] + obp[o0+r];
    *(f32x4*)(orow + o0) = ov;
  }
}

// ---------------------------------------------------------------------------
extern "C" void kernel_launch(void* const* d_in, const int* in_sizes, int n_in,
                              void* d_out, int out_size, void* d_ws, size_t ws_size,
                              hipStream_t stream)
{
  const float* x  = (const float*)d_in[0];
  const float* Wf = (const float*)d_in[1];
  const float* bf = (const float*)d_in[2];
  const float* Wi = (const float*)d_in[3];
  const float* bi = (const float*)d_in[4];
  const float* Wo = (const float*)d_in[5];
  const float* bo = (const float*)d_in[6];
  const float* Wc = (const float*)d_in[7];
  const float* bc = (const float*)d_in[8];
  const float* ow = (const float*)d_in[9];
  const float* ob = (const float*)d_in[10];
  float* out = (float*)d_out;

  // workspace: fixed 270336 B (flags 8K + hbuf 128K bf16 + cbuf 128K f32)
  //          + CH*589824 B (xg fp32 CH*512K + hs bf16 CH*64K)
  const size_t fixed = 270336;
  int CH = 256, chlog = 8;
  while (CH > 16 && fixed + (size_t)CH*589824 > ws_size){ CH >>= 1; chlog--; }
  const int NC = 512 / CH;

  char* ws = (char*)d_ws;
  unsigned* flags = (unsigned*)ws;                     // 8 KB (64 x 128B)
  u16*   hbuf = (u16*)(ws + 8192);                     // 128 KB
  float* cbuf = (float*)(ws + 139264);                 // 128 KB
  float* xg   = (float*)(ws + 270336);                 // CH*512 KB
  u16*   hsc  = (u16*)(ws + 270336 + (size_t)CH*524288); // CH*64 KB
  float* hfin = out + (size_t)8388608;
  float* cfin = out + (size_t)8421376;

  hipMemsetAsync(ws, 0, fixed, stream);  // flags=0, h(0)=0, c(0)=0

  for(int c=0; c<NC; ++c){
    int t0 = c*CH;
    k_xg<<<dim3(64,CH/8),256,0,stream>>>(x,Wf,Wi,Wo,Wc,bf,bi,bo,bc,xg,t0);

    const float* a_xg = xg;
    int a_t0 = t0, a_ch = CH;
    void* args[] = { (void*)&a_xg, (void*)&Wf, (void*)&Wi, (void*)&Wo, (void*)&Wc,
                     (void*)&hbuf, (void*)&hsc, (void*)&hfin, (void*)&cfin,
                     (void*)&cbuf, (void*)&flags, (void*)&a_t0, (void*)&a_ch };
    hipLaunchCooperativeKernel((const void*)k_rec, dim3(64), dim3(256), args, 0, stream);

    k_out<<<dim3(CH/2,8),256,0,stream>>>(hsc, ow, ob, out, t0, chlog);
  }
}

// Round 8
// 3698.230 us; speedup vs baseline: 1.3422x; 1.1518x over previous
//
#include <hip/hip_runtime.h>

typedef unsigned short u16;
typedef unsigned long long u64;
typedef __attribute__((ext_vector_type(8))) short short8;
typedef __attribute__((ext_vector_type(4))) float f32x4;
typedef __attribute__((ext_vector_type(2))) float f32x2;

#define S_ 512
#define I_ 512
#define H_ 1024
#define B_ 32
#define G_ 4096   // 4*H
#define WROW 1536 // I+H

__device__ __forceinline__ u16 f2b(float f){ union{float f;unsigned u;}c; c.f=f; unsigned u=c.u; return (u16)((u + 0x7FFFu + ((u>>16)&1u))>>16); }

// pack two fp32 (already bf16-rounded) into two bf16 lanes by truncation (exact)
// NOTE: v_perm_b32 variant broke correctness in R4; shifts are proven.
__device__ __forceinline__ unsigned pk2(float a, float b){
  union{float f;unsigned u;} x, y; x.f=a; y.f=b;
  return (x.u>>16) | (y.u & 0xffff0000u);
}
// 8 consecutive fp32 -> short8 bf16 fragment
__device__ __forceinline__ short8 cvt8(const float* __restrict__ p){
  f32x4 a = *(const f32x4*)p;
  f32x4 b = *(const f32x4*)(p+4);
  union{unsigned u[4]; short8 s;} r;
  r.u[0]=pk2(a[0],a[1]); r.u[1]=pk2(a[2],a[3]);
  r.u[2]=pk2(b[0],b[1]); r.u[3]=pk2(b[2],b[3]);
  return r.s;
}

__device__ __forceinline__ f32x4 mfma16(short8 a, short8 b, f32x4 c){
  return __builtin_amdgcn_mfma_f32_16x16x32_bf16(a,b,c,0,0,0);
}
__device__ __forceinline__ float sigf(float x){ return 1.0f/(1.0f+__expf(-x)); }
__device__ __forceinline__ float tanhfast(float x){ return 1.0f - 2.0f/(__expf(2.0f*x)+1.0f); }

// ---------------------------------------------------------------------------
// Phase 1 (per chunk): xg[sl][g][b] = sum_i x[b][t0+sl][i]*W[g][i] + bias[g]
// (unchanged from R7)
// ---------------------------------------------------------------------------
__global__ __launch_bounds__(256,2) void k_xg(
    const float* __restrict__ x,
    const float* __restrict__ Wf, const float* __restrict__ Wi,
    const float* __restrict__ Wo, const float* __restrict__ Wc,
    const float* __restrict__ bfp, const float* __restrict__ bip,
    const float* __restrict__ bop, const float* __restrict__ bcp,
    float* __restrict__ xg, int t0)
{
  const int gt = blockIdx.x;
  const int sg = blockIdx.y;
  const int wv = threadIdx.x>>6;
  const int ln = threadIdx.x&63;
  const int n16 = ln&15, qd = ln>>4;
  const int g0 = gt*64 + wv*16;
  const int q = g0>>10, j0 = g0&1023;
  const float* W  = (q==0)?Wf:(q==1)?Wi:(q==2)?Wo:Wc;
  const float* bb = (q==0)?bfp:(q==1)?bip:(q==2)?bop:bcp;

  short8 Bf[16];
  {
    const float* wr = W + (size_t)(j0+n16)*WROW + qd*8;
    #pragma unroll
    for(int kt=0;kt<16;++kt) Bf[kt] = cvt8(wr + kt*32);
  }
  const float bv = bb[j0+n16];

  for(int si=0; si<8; ++si){
    const int sl = sg*8 + si;
    const int s  = t0 + sl;
    const float* xp = x + (size_t)n16*(S_*I_) + (size_t)s*I_ + qd*8;
    f32x4 a0={0,0,0,0}, a1={0,0,0,0};
    #pragma unroll
    for(int kt=0;kt<16;++kt){
      short8 A0 = cvt8(xp + kt*32);
      short8 A1 = cvt8(xp + (size_t)16*(S_*I_) + kt*32);
      a0 = mfma16(A0, Bf[kt], a0);
      a1 = mfma16(A1, Bf[kt], a1);
    }
    float* op = xg + ((size_t)sl*G_ + g0 + n16)*B_ + qd*4;
    f32x4 o0, o1;
    #pragma unroll
    for(int r=0;r<4;++r){ o0[r]=a0[r]+bv; o1[r]=a1[r]+bv; }
    *(f32x4*)op = o0;
    *(f32x4*)(op+16) = o1;
  }
}

// ---------------------------------------------------------------------------
// Phase 2: persistent cooperative recurrence, unique-address protocol.
// h(t+1) is written ONCE into hs[tl] (fresh addresses every step) via
// agent-scope write-through atomics; after the flag-gate, consumers read
// hs[tl-1] with PLAIN CACHED loads. A line can't be stale in any L2:
// dispatch boundaries invalidate caches, and within the kernel the first
// touch of an hs[tl] line on any XCD is after the flag (=> after the
// producer's LLC write-through). LLC read traffic drops 8x (L2 shares
// within an XCD) and the shadow hbuf store stream disappears.
// Chunk carry: hprev (plain stores/loads across dispatch boundaries).
// ---------------------------------------------------------------------------
__global__ __launch_bounds__(256,1) void k_rec(
  const float* __restrict__ xg,
  const float* __restrict__ Wf, const float* __restrict__ Wi,
  const float* __restrict__ Wo, const float* __restrict__ Wc,
  u16* __restrict__ hprev,  // [32][1024] bf16 carry (chunk boundary)
  u16* __restrict__ hs,     // [32][CH][1024] bf16 — THE h exchange buffer
  float* __restrict__ hfin, float* __restrict__ cfin,
  float* __restrict__ cbuf, // [32][1024] f32
  unsigned* __restrict__ flags, // 64 x 32 u32 (128B apart), monotone
  int t0, int CH)
{
  const int bid = blockIdx.x;
  const int h0  = bid*16;
  const int tid = threadIdx.x;
  const int kw  = tid>>6;          // wave index = K-slice
  const int ln  = tid&63;
  const int n16 = ln&15, qd = ln>>4;

  __shared__ float pbuf[4][4][16][38]; // [kw][q][hi][b+pad]

  // Wh B-frags: Bf[q][k], k-slice = kw*256 .. +255  (fp32 -> bf16, exact)
  short8 Bf[4][8];
  {
    const int kcol = 512 + kw*256 + qd*8;
    const float* w0 = Wf + (size_t)(h0+n16)*WROW + kcol;
    const float* w1 = Wi + (size_t)(h0+n16)*WROW + kcol;
    const float* w2 = Wo + (size_t)(h0+n16)*WROW + kcol;
    const float* w3 = Wc + (size_t)(h0+n16)*WROW + kcol;
    #pragma unroll
    for(int k=0;k<8;++k){
      Bf[0][k] = cvt8(w0 + k*32);
      Bf[1][k] = cvt8(w1 + k*32);
      Bf[2][k] = cvt8(w2 + k*32);
      Bf[3][k] = cvt8(w3 + k*32);
    }
  }

  const int ub  = tid>>3;        // b (0..31)
  const int hi0 = (tid&7)*2;     // hi pair {hi0, hi0+1}
  f32x2 c01 = *(const f32x2*)(cbuf + (size_t)ub*H_ + h0 + hi0);

  for(int tl=0; tl<CH; ++tl){
    const int t = t0 + tl;
    // xg prefetch for the cell update (independent of h(t))
    float xv[2][4];
    {
      const float* xp = xg + ((size_t)tl*G_ + h0 + hi0)*B_ + ub;
      #pragma unroll
      for(int q=0;q<4;++q){
        xv[0][q] = xp[(size_t)q*1024*B_];
        xv[1][q] = xp[(size_t)q*1024*B_ + B_];
      }
    }
    if (t>0){
      if (tid < 64){
        const unsigned goal = (unsigned)t;
        unsigned v;
        do {
          v = __hip_atomic_load(flags + (tid<<5), __ATOMIC_RELAXED, __HIP_MEMORY_SCOPE_AGENT);
          if (__ballot(v < goal) == 0ull) break;
          __builtin_amdgcn_s_sleep(1);
        } while (true);
        // no fence needed: hs[tl-1] lines are first-touch-after-flag
      }
      __syncthreads();
    }
    // A-frags: h(t) rows (bf16), this wave's K-slice — PLAIN cached loads
    const u16* hbase; size_t bstride;
    if (tl==0){ hbase = hprev;                    bstride = H_; }
    else      { hbase = hs + (size_t)(tl-1)*H_;   bstride = (size_t)CH*H_; }
    const int kcolq = kw*256 + qd*8;
    const u16* hp0 = hbase + (size_t)n16*bstride      + kcolq;
    const u16* hp1 = hbase + (size_t)(16+n16)*bstride + kcolq;
    f32x4 acc[2][4];
    #pragma unroll
    for(int m=0;m<2;++m)
      #pragma unroll
      for(int q=0;q<4;++q) acc[m][q]=(f32x4){0.f,0.f,0.f,0.f};
    #pragma unroll
    for(int k=0;k<8;++k){
      short8 A0 = *(const short8*)(hp0 + k*32);
      short8 A1 = *(const short8*)(hp1 + k*32);
      #pragma unroll
      for(int q=0;q<4;++q){
        acc[0][q] = mfma16(A0, Bf[q][k], acc[0][q]);
        acc[1][q] = mfma16(A1, Bf[q][k], acc[1][q]);
      }
    }
    // partial-sum exchange: D col = gate sub-index (n16), rows = b
    #pragma unroll
    for(int m=0;m<2;++m)
      #pragma unroll
      for(int q=0;q<4;++q){
        float* dst = &pbuf[kw][q][n16][m*16 + qd*4];
        *(f32x2*)dst       = (f32x2){acc[m][q][0], acc[m][q][1]};
        *(f32x2*)(dst + 2) = (f32x2){acc[m][q][2], acc[m][q][3]};
      }
    __syncthreads();
    // cell update: thread handles (b=ub, hi=hi0) and (b=ub, hi=hi0+1)
    float g[2][4];
    #pragma unroll
    for(int e=0;e<2;++e){
      #pragma unroll
      for(int q=0;q<4;++q){
        g[e][q] = xv[e][q] + pbuf[0][q][hi0+e][ub] + pbuf[1][q][hi0+e][ub]
                           + pbuf[2][q][hi0+e][ub] + pbuf[3][q][hi0+e][ub];
      }
    }
    float hv[2], cn[2];
    #pragma unroll
    for(int e=0;e<2;++e){
      float fg = sigf(g[e][0]);
      float ig = sigf(g[e][1]);
      float og = sigf(g[e][2]);
      float ch = tanhfast(g[e][3]);
      cn[e] = fg*c01[e] + ig*ch;
      hv[e] = og*tanhfast(cn[e]);
      c01[e] = cn[e];
    }
    const unsigned hpk = (unsigned)f2b(hv[0]) | ((unsigned)f2b(hv[1])<<16);
    // h(t+1): single write-through store into hs[tl] (agent-scope atomic)
    unsigned* hw = (unsigned*)(hs + ((size_t)ub*CH + tl)*H_ + h0 + hi0);
    __hip_atomic_store(hw, hpk, __ATOMIC_RELAXED, __HIP_MEMORY_SCOPE_AGENT);
    if (tl==CH-1)   // chunk carry for next dispatch (plain, flushed at end)
      *(unsigned*)(hprev + (size_t)ub*H_ + h0 + hi0) = hpk;
    if (t==511){
      *(f32x2*)(hfin + (size_t)ub*H_ + h0 + hi0) = (f32x2){hv[0], hv[1]};
      *(f32x2*)(cfin + (size_t)ub*H_ + h0 + hi0) = (f32x2){cn[0], cn[1]};
    }
    if (tl==CH-1)
      *(f32x2*)(cbuf + (size_t)ub*H_ + h0 + hi0) = c01;
    __syncthreads();              // vmcnt(0): hs stores ack'd at LLC
    if (tid==0)
      __hip_atomic_store(flags + (bid<<5), (unsigned)(t+1),
                         __ATOMIC_RELAXED, __HIP_MEMORY_SCOPE_AGENT);
  }
}

// ---------------------------------------------------------------------------
// Phase 3 (per chunk): out[b][t0+sl][o] = sum_h hs[b][sl][h]*ow[o][h] + ob[o]
// (unchanged from R7)
// ---------------------------------------------------------------------------
__global__ __launch_bounds__(256,2) void k_out(
  const u16* __restrict__ hs,
  const float* __restrict__ ow,
  const float* __restrict__ obp,
  float* __restrict__ out, int t0, int chlog)
{
  const int bst = blockIdx.x;
  const int ot  = blockIdx.y;
  const int wv = threadIdx.x>>6;
  const int ln = threadIdx.x&63;
  const int n16 = ln&15, qd = ln>>4;
  const int bs0 = bst*64 + wv*16 + n16;   // row in hs_chunk = b*CH + sl
  const u16* bp   = hs + (size_t)bs0*H_ + qd*8;
  const float* ap = ow + (size_t)(ot*64 + n16)*H_ + qd*8;
  f32x4 acc[4];
  #pragma unroll
  for(int m=0;m<4;++m) acc[m]=(f32x4){0.f,0.f,0.f,0.f};
  #pragma unroll 4
  for(int kt=0;kt<32;++kt){
    short8 Bfr = *(const short8*)(bp + kt*32);
    #pragma unroll
    for(int m=0;m<4;++m){
      short8 Afr = cvt8(ap + (size_t)m*16*H_ + kt*32);
      acc[m] = mfma16(Afr, Bfr, acc[m]);
    }
  }
  const int b  = bs0 >> chlog;
  const int sl = bs0 & ((1<<chlog)-1);
  float* orow = out + ((size_t)b*S_ + t0 + sl)*512;
  #pragma unroll
  for(int m=0;m<4;++m){
    const int o0 = ot*64 + m*16 + qd*4;
    f32x4 ov;
    #pragma unroll
    for(int r=0;r<4;++r) ov[r] = acc[m][r] + obp[o0+r];
    *(f32x4*)(orow + o0) = ov;
  }
}

// ---------------------------------------------------------------------------
extern "C" void kernel_launch(void* const* d_in, const int* in_sizes, int n_in,
                              void* d_out, int out_size, void* d_ws, size_t ws_size,
                              hipStream_t stream)
{
  const float* x  = (const float*)d_in[0];
  const float* Wf = (const float*)d_in[1];
  const float* bf = (const float*)d_in[2];
  const float* Wi = (const float*)d_in[3];
  const float* bi = (const float*)d_in[4];
  const float* Wo = (const float*)d_in[5];
  const float* bo = (const float*)d_in[6];
  const float* Wc = (const float*)d_in[7];
  const float* bc = (const float*)d_in[8];
  const float* ow = (const float*)d_in[9];
  const float* ob = (const float*)d_in[10];
  float* out = (float*)d_out;

  // workspace: fixed 204800 B (flags 8K + hprev 64K + cbuf 128K)
  //          + CH*589824 B (xg fp32 CH*512K + hs bf16 CH*64K)
  const size_t fixed = 204800;
  int CH = 256, chlog = 8;
  while (CH > 16 && fixed + (size_t)CH*589824 > ws_size){ CH >>= 1; chlog--; }
  const int NC = 512 / CH;

  char* ws = (char*)d_ws;
  unsigned* flags = (unsigned*)ws;                     // 8 KB (64 x 128B)
  u16*   hprev = (u16*)(ws + 8192);                    // 64 KB
  float* cbuf  = (float*)(ws + 73728);                 // 128 KB
  float* xg    = (float*)(ws + 204800);                // CH*512 KB
  u16*   hsc   = (u16*)(ws + 204800 + (size_t)CH*524288); // CH*64 KB
  float* hfin = out + (size_t)8388608;
  float* cfin = out + (size_t)8421376;

  hipMemsetAsync(ws, 0, fixed, stream);  // flags=0, h(0)=0, c(0)=0

  for(int c=0; c<NC; ++c){
    int t0 = c*CH;
    k_xg<<<dim3(64,CH/8),256,0,stream>>>(x,Wf,Wi,Wo,Wc,bf,bi,bo,bc,xg,t0);

    const float* a_xg = xg;
    int a_t0 = t0, a_ch = CH;
    void* args[] = { (void*)&a_xg, (void*)&Wf, (void*)&Wi, (void*)&Wo, (void*)&Wc,
                     (void*)&hprev, (void*)&hsc, (void*)&hfin, (void*)&cfin,
                     (void*)&cbuf, (void*)&flags, (void*)&a_t0, (void*)&a_ch };
    hipLaunchCooperativeKernel((const void*)k_rec, dim3(64), dim3(256), args, 0, stream);

    k_out<<<dim3(CH/2,8),256,0,stream>>>(hsc, ow, ob, out, t0, chlog);
  }
}